// Round 11
// baseline (1398.897 us; speedup 1.0000x reference)
//
#include <hip/hip_runtime.h>
#include <hip/hip_fp16.h>
#include <cstdint>
#include <cstddef>

// OwnVanillaRNN R11: octet-sliced weight-stationary RNN (R10 + 2 fixes).
// R10 bug: row_ror:4 direction backwards (AMD DPP shr/ror move data toward
// HIGHER lanes: dst[i]=src[i-N mod 16]) -> writer summed the WRONG octet's
// quad. Fix: ROW_HALF_MIRROR (0x141), symmetric (lane i <-> 7-(i&7) within
// each 8-half-row) -> every lane ends with the full 8-slice sum; cannot be
// direction-wrong. Also: MA asm gains a loop-variant dummy input (hv.x) so
// LICM can't hoist the 128 accvgpr_reads out of the loop (would re-spill).
// Structure: thread = (8 rows x 72-dim slice); weights V21/A32/L19;
// ~224 DS b128 issues/CU/step; double-buffered h; ONE barrier/step.

constexpr int BATCH = 256;
constexpr int SEQ   = 512;
constexpr int IN    = 64;
constexpr int HID   = 512;
constexpr int OUT   = 64;
constexpr int T     = 512;        // threads
constexpr int DTOT  = HID + IN;   // 576
constexpr int DSL   = DTOT / 8;   // 72 dims per slice
constexpr int NL    = 19;         // LDS frags per thread (k = 53..71)
constexpr int KL0   = 53;

typedef _Float16 half2v __attribute__((ext_vector_type(2)));

__device__ __forceinline__ float fdot2(uint32_t w, uint32_t h, float acc) {
    return __builtin_amdgcn_fdot2(__builtin_bit_cast(half2v, w),
                                  __builtin_bit_cast(half2v, h), acc, false);
}
__device__ __forceinline__ uint32_t packh2(float lo, float hi) {
    return (uint32_t)__half_as_ushort(__float2half(lo)) |
           ((uint32_t)__half_as_ushort(__float2half(hi)) << 16);
}
// DPP add: 0xB1 quad[1,0,3,2] (xor1), 0x4E quad[2,3,0,1] (xor2),
// 0x141 ROW_HALF_MIRROR (lane i <-> 7-(i&7) in each 8-lane half-row).
// All three are symmetric -> full 8-lane sum lands in EVERY lane.
template <int CTRL>
__device__ __forceinline__ float dpp_add(float v) {
    int i = __builtin_bit_cast(int, v);
    int p = __builtin_amdgcn_update_dpp(i, i, CTRL, 0xF, 0xF, false);
    return v + __builtin_bit_cast(float, p);
}

// Frag k (0..71): p = k>>3 (dim position), r = k&7 (row in octet).
// Thread t: g = t>>3, s = t&7. Weight = W~[8g+r][72s+8p .. +7] f16,
// W~[o] = [Wh[o][0..511] ; Wx[o][0..63]]. d0 = 72s+8p is 8-aligned -> no
// fragment straddles the Wh/Wx boundary.
__global__ __launch_bounds__(256, 1)
void prep_w(const float* __restrict__ Wh, const float* __restrict__ Wx,
            uint4* __restrict__ Wpk) {
    const int idx = blockIdx.x * 256 + threadIdx.x;   // 72*512
    const int k = idx >> 9, t = idx & (T - 1);
    const int p = k >> 3, r = k & 7;
    const int g = t >> 3, s = t & 7;
    const int o = 8 * g + r;
    const int d0 = DSL * s + 8 * p;
    const float* src = (d0 < HID) ? (Wh + (size_t)o * HID + d0)
                                  : (Wx + (size_t)o * IN + (d0 - HID));
    uint4 d;
    d.x = packh2(src[0], src[1]);
    d.y = packh2(src[2], src[3]);
    d.z = packh2(src[4], src[5]);
    d.w = packh2(src[6], src[7]);
    Wpk[idx] = d;
}

#define AG_LIST(M) \
  M(21) M(22) M(23) M(24) M(25) M(26) M(27) M(28) M(29) M(30) M(31) \
  M(32) M(33) M(34) M(35) M(36) M(37) M(38) M(39) M(40) M(41) M(42) \
  M(43) M(44) M(45) M(46) M(47) M(48) M(49) M(50) M(51) M(52)

// MAC helpers; hv must be in scope. Param Z must not collide with x/y/z/w
// (R9 lesson). MA: non-volatile (schedulable, outputs used so no DCE) but
// with hv.x as dummy input -> loop-VARIANT -> LICM cannot hoist the reads
// out of the step loop (which would create 128 live VGPRs and spill).
#define MV(f, Z) { \
    Z = fdot2(w##f.x, hv.x, Z); Z = fdot2(w##f.y, hv.y, Z); \
    Z = fdot2(w##f.z, hv.z, Z); Z = fdot2(w##f.w, hv.w, Z); }
#define MA(f, Z) { uint32_t q0, q1, q2, q3; \
    asm("v_accvgpr_read_b32 %0, %1" : "=v"(q0) : "a"(ag##f##_0), "v"(hv.x)); \
    asm("v_accvgpr_read_b32 %0, %1" : "=v"(q1) : "a"(ag##f##_1), "v"(hv.x)); \
    asm("v_accvgpr_read_b32 %0, %1" : "=v"(q2) : "a"(ag##f##_2), "v"(hv.x)); \
    asm("v_accvgpr_read_b32 %0, %1" : "=v"(q3) : "a"(ag##f##_3), "v"(hv.x)); \
    Z = fdot2(q0, hv.x, Z); Z = fdot2(q1, hv.y, Z); \
    Z = fdot2(q2, hv.z, Z); Z = fdot2(q3, hv.w, Z); }
#define ML(i, Z) { const uint4 wv = wl[t * NL + (i)]; \
    Z = fdot2(wv.x, hv.x, Z); Z = fdot2(wv.y, hv.y, Z); \
    Z = fdot2(wv.z, hv.z, Z); Z = fdot2(wv.w, hv.w, Z); }

__global__ __launch_bounds__(T, 2)
__attribute__((amdgpu_waves_per_eu(2, 2)))
void rnn_main(const float* __restrict__ x,  const float* __restrict__ bx,
              const float* __restrict__ bh, const float* __restrict__ Wy,
              const float* __restrict__ by, const uint4* __restrict__ Wpk,
              float* __restrict__ y) {
    __shared__ uint4 wl[T * NL];                     // 152 KB, transposed
    __shared__ __align__(16) __half hb2[2][DTOT];    // double-buffered h~

    const int b = blockIdx.x, t = threadIdx.x;
    const int g = t >> 3, s = t & 7;

    // ---- one-time: LDS weights (per-thread contiguous, stride 304 B) ----
    #pragma unroll
    for (int i = 0; i < NL; ++i)
        wl[t * NL + i] = Wpk[(size_t)(KL0 + i) * T + t];

    // ---- one-time: VGPR frags w0..w20 (named SSA) ----
#define DECL_WV(f) const uint4 w##f = Wpk[(size_t)(f) * T + t];
    DECL_WV(0)  DECL_WV(1)  DECL_WV(2)  DECL_WV(3)  DECL_WV(4)  DECL_WV(5)
    DECL_WV(6)  DECL_WV(7)  DECL_WV(8)  DECL_WV(9)  DECL_WV(10) DECL_WV(11)
    DECL_WV(12) DECL_WV(13) DECL_WV(14) DECL_WV(15) DECL_WV(16) DECL_WV(17)
    DECL_WV(18) DECL_WV(19) DECL_WV(20)
#undef DECL_WV

    // ---- one-time: AGPR frags ag21..ag52 (128 AGPRs) ----
#define DECL_AG(f) uint32_t ag##f##_0, ag##f##_1, ag##f##_2, ag##f##_3;
    AG_LIST(DECL_AG)
#undef DECL_AG
#define LOAD_AG(f) { const uint4 tmp = Wpk[(size_t)(f) * T + t]; \
    asm("v_accvgpr_write_b32 %0, %1" : "=a"(ag##f##_0) : "v"(tmp.x)); \
    asm("v_accvgpr_write_b32 %0, %1" : "=a"(ag##f##_1) : "v"(tmp.y)); \
    asm("v_accvgpr_write_b32 %0, %1" : "=a"(ag##f##_2) : "v"(tmp.z)); \
    asm("v_accvgpr_write_b32 %0, %1" : "=a"(ag##f##_3) : "v"(tmp.w)); }
    AG_LIST(LOAD_AG)
#undef LOAD_AG

    // Row biases (used by writer lanes s==0; rows 8g..8g+7).
    const float bs0 = bx[8*g+0] + bh[8*g+0], bs1 = bx[8*g+1] + bh[8*g+1];
    const float bs2 = bx[8*g+2] + bh[8*g+2], bs3 = bx[8*g+3] + bh[8*g+3];
    const float bs4 = bx[8*g+4] + bh[8*g+4], bs5 = bx[8*g+5] + bh[8*g+5];
    const float bs6 = bx[8*g+6] + bh[8*g+6], bs7 = bx[8*g+7] + bh[8*g+7];

    const float* xb = x + (size_t)b * SEQ * IN;

    hb2[0][t] = __float2half(0.0f);                     // h0 = 0
    if (t < IN) hb2[0][HID + t] = __float2half(xb[t]);  // x_0
    float xv = (t < IN) ? xb[IN + t] : 0.0f;            // x_1 prefetched
    __syncthreads();

    #pragma unroll 1
    for (int tt = 0; tt < SEQ; ++tt) {
        const int c = tt & 1;
        const uint4* hb = (const uint4*)(&hb2[c][0] + DSL * s);
        float z0 = 0.f, z1 = 0.f, z2 = 0.f, z3 = 0.f;
        float z4 = 0.f, z5 = 0.f, z6 = 0.f, z7 = 0.f;

        { const uint4 hv = hb[0];                      // k 0..7   (V)
          MV(0,z0) MV(1,z1) MV(2,z2) MV(3,z3) MV(4,z4) MV(5,z5) MV(6,z6) MV(7,z7) }
        { const uint4 hv = hb[1];                      // k 8..15  (V)
          MV(8,z0) MV(9,z1) MV(10,z2) MV(11,z3) MV(12,z4) MV(13,z5) MV(14,z6) MV(15,z7) }
        { const uint4 hv = hb[2];                      // k 16..23 (V,A)
          MV(16,z0) MV(17,z1) MV(18,z2) MV(19,z3) MV(20,z4) MA(21,z5) MA(22,z6) MA(23,z7) }
        { const uint4 hv = hb[3];                      // k 24..31 (A)
          MA(24,z0) MA(25,z1) MA(26,z2) MA(27,z3) MA(28,z4) MA(29,z5) MA(30,z6) MA(31,z7) }
        { const uint4 hv = hb[4];                      // k 32..39 (A)
          MA(32,z0) MA(33,z1) MA(34,z2) MA(35,z3) MA(36,z4) MA(37,z5) MA(38,z6) MA(39,z7) }
        { const uint4 hv = hb[5];                      // k 40..47 (A)
          MA(40,z0) MA(41,z1) MA(42,z2) MA(43,z3) MA(44,z4) MA(45,z5) MA(46,z6) MA(47,z7) }
        { const uint4 hv = hb[6];                      // k 48..55 (A,L)
          MA(48,z0) MA(49,z1) MA(50,z2) MA(51,z3) MA(52,z4) ML(0,z5) ML(1,z6) ML(2,z7) }
        { const uint4 hv = hb[7];                      // k 56..63 (L)
          ML(3,z0) ML(4,z1) ML(5,z2) ML(6,z3) ML(7,z4) ML(8,z5) ML(9,z6) ML(10,z7) }
        { const uint4 hv = hb[8];                      // k 64..71 (L)
          ML(11,z0) ML(12,z1) ML(13,z2) ML(14,z3) ML(15,z4) ML(16,z5) ML(17,z6) ML(18,z7) }

        // 8-way K-reduce: quad xor1 + xor2 (quad sums), then HALF_MIRROR adds
        // the sibling quad's sum -> every lane holds the full 8-slice sum.
        z0 = dpp_add<0xB1>(z0); z0 = dpp_add<0x4E>(z0); z0 = dpp_add<0x141>(z0);
        z1 = dpp_add<0xB1>(z1); z1 = dpp_add<0x4E>(z1); z1 = dpp_add<0x141>(z1);
        z2 = dpp_add<0xB1>(z2); z2 = dpp_add<0x4E>(z2); z2 = dpp_add<0x141>(z2);
        z3 = dpp_add<0xB1>(z3); z3 = dpp_add<0x4E>(z3); z3 = dpp_add<0x141>(z3);
        z4 = dpp_add<0xB1>(z4); z4 = dpp_add<0x4E>(z4); z4 = dpp_add<0x141>(z4);
        z5 = dpp_add<0xB1>(z5); z5 = dpp_add<0x4E>(z5); z5 = dpp_add<0x141>(z5);
        z6 = dpp_add<0xB1>(z6); z6 = dpp_add<0x4E>(z6); z6 = dpp_add<0x141>(z6);
        z7 = dpp_add<0xB1>(z7); z7 = dpp_add<0x4E>(z7); z7 = dpp_add<0x141>(z7);

        if (s == 0) {
            // tanh via 1 - 2/(e^{2z}+1); rcp degrades gracefully to +-1.
            const float h0 = 1.f - 2.f * __builtin_amdgcn_rcpf(__expf(2.f*(z0+bs0)) + 1.f);
            const float h1 = 1.f - 2.f * __builtin_amdgcn_rcpf(__expf(2.f*(z1+bs1)) + 1.f);
            const float h2 = 1.f - 2.f * __builtin_amdgcn_rcpf(__expf(2.f*(z2+bs2)) + 1.f);
            const float h3 = 1.f - 2.f * __builtin_amdgcn_rcpf(__expf(2.f*(z3+bs3)) + 1.f);
            const float h4 = 1.f - 2.f * __builtin_amdgcn_rcpf(__expf(2.f*(z4+bs4)) + 1.f);
            const float h5 = 1.f - 2.f * __builtin_amdgcn_rcpf(__expf(2.f*(z5+bs5)) + 1.f);
            const float h6 = 1.f - 2.f * __builtin_amdgcn_rcpf(__expf(2.f*(z6+bs6)) + 1.f);
            const float h7 = 1.f - 2.f * __builtin_amdgcn_rcpf(__expf(2.f*(z7+bs7)) + 1.f);
            uint4 pk;
            pk.x = packh2(h0, h1); pk.y = packh2(h2, h3);
            pk.z = packh2(h4, h5); pk.w = packh2(h6, h7);
            *(uint4*)(&hb2[c ^ 1][0] + 8 * g) = pk;    // rows 8g..8g+7
        }
        if (t < IN) {
            hb2[c ^ 1][HID + t] = __float2half(xv);    // x_{tt+1}
            if (tt + 2 < SEQ) xv = xb[(size_t)(tt + 2) * IN + t];
        }
        __syncthreads();
    }

    // ---- epilogue: y = h_T @ Wy^T + by (final h in buffer 0) ----
    if (t < OUT) {
        float acc = by[t];
        const float* wy = Wy + (size_t)t * HID;
        #pragma unroll 8
        for (int j = 0; j < HID; ++j)
            acc = fmaf(wy[j], __half2float(hb2[0][j]), acc);
        y[(size_t)b * OUT + t] = acc;
    }
}

extern "C" void kernel_launch(void* const* d_in, const int* in_sizes, int n_in,
                              void* d_out, int out_size, void* d_ws, size_t ws_size,
                              hipStream_t stream) {
    const float* x  = (const float*)d_in[0];
    const float* Wx = (const float*)d_in[1];
    const float* bx = (const float*)d_in[2];
    const float* Wh = (const float*)d_in[3];
    const float* bh = (const float*)d_in[4];
    const float* Wy = (const float*)d_in[5];
    const float* by = (const float*)d_in[6];
    float* y = (float*)d_out;

    uint4* Wpk = (uint4*)d_ws;  // 72*512*16 B = 576 KB packed f16 fragments

    hipLaunchKernelGGL(prep_w, dim3(72 * T / 256), dim3(256), 0, stream,
                       Wh, Wx, Wpk);
    hipLaunchKernelGGL(rnn_main, dim3(BATCH), dim3(T), 0, stream,
                       x, bx, bh, Wy, by, Wpk, y);
}

// Round 12
// 879.198 us; speedup vs baseline: 1.5911x; 1.5911x over previous
//
#include <hip/hip_runtime.h>
#include <hip/hip_fp16.h>
#include <cstdint>
#include <cstddef>

// OwnVanillaRNN R12: octet-sliced weight-stationary, COMPILER-native AGPRs.
// R8/R11 lesson: hand accvgpr asm loses every way (volatile=serialized,
// plain=LICM-hoisted->spill, dummy-dep=chained on DS latency). Instead:
// all 53 reg frags are plain named SSA; a one-time opaque asm touches a127
// so the attributor doesn't mark amdgpu-no-agpr -> the register allocator
// spills the overflow (~29 frags) to AGPRs ITSELF with schedulable
// v_accvgpr moves. Also: all-lane epilogue (select z_s via 7 cndmask after
// the symmetric 8-lane reduce; 1 tanh + contiguous ds_write_b16 per lane)
// replaces the exec-masked 8-exp s==0 block.

constexpr int BATCH = 256;
constexpr int SEQ   = 512;
constexpr int IN    = 64;
constexpr int HID   = 512;
constexpr int OUT   = 64;
constexpr int T     = 512;        // threads
constexpr int DTOT  = HID + IN;   // 576
constexpr int DSL   = DTOT / 8;   // 72 dims per slice
constexpr int NL    = 19;         // LDS frags per thread (k = 53..71)
constexpr int KL0   = 53;

typedef _Float16 half2v __attribute__((ext_vector_type(2)));

__device__ __forceinline__ float fdot2(uint32_t w, uint32_t h, float acc) {
    return __builtin_amdgcn_fdot2(__builtin_bit_cast(half2v, w),
                                  __builtin_bit_cast(half2v, h), acc, false);
}
__device__ __forceinline__ uint32_t packh2(float lo, float hi) {
    return (uint32_t)__half_as_ushort(__float2half(lo)) |
           ((uint32_t)__half_as_ushort(__float2half(hi)) << 16);
}
// DPP add: 0xB1 quad xor1, 0x4E quad xor2, 0x141 ROW_HALF_MIRROR.
// All symmetric -> full 8-lane-group sum lands in EVERY lane (R11-verified).
template <int CTRL>
__device__ __forceinline__ float dpp_add(float v) {
    int i = __builtin_bit_cast(int, v);
    int p = __builtin_amdgcn_update_dpp(i, i, CTRL, 0xF, 0xF, false);
    return v + __builtin_bit_cast(float, p);
}

// Frag k (0..71): p = k>>3 (dim position), r = k&7 (row in octet).
// Thread t: g = t>>3, s = t&7. Weight = W~[8g+r][72s+8p .. +7] f16,
// W~[o] = [Wh[o] ; Wx[o]]. d0 = 72s+8p is 8-aligned (no boundary straddle).
__global__ __launch_bounds__(256, 1)
void prep_w(const float* __restrict__ Wh, const float* __restrict__ Wx,
            uint4* __restrict__ Wpk) {
    const int idx = blockIdx.x * 256 + threadIdx.x;   // 72*512
    const int k = idx >> 9, t = idx & (T - 1);
    const int p = k >> 3, r = k & 7;
    const int g = t >> 3, s = t & 7;
    const int o = 8 * g + r;
    const int d0 = DSL * s + 8 * p;
    const float* src = (d0 < HID) ? (Wh + (size_t)o * HID + d0)
                                  : (Wx + (size_t)o * IN + (d0 - HID));
    uint4 d;
    d.x = packh2(src[0], src[1]);
    d.y = packh2(src[2], src[3]);
    d.z = packh2(src[4], src[5]);
    d.w = packh2(src[6], src[7]);
    Wpk[idx] = d;
}

// MAC helpers; hv in scope. Param Z: no x/y/z/w collision (R9 lesson).
#define MV(f, Z) { \
    Z = fdot2(w##f.x, hv.x, Z); Z = fdot2(w##f.y, hv.y, Z); \
    Z = fdot2(w##f.z, hv.z, Z); Z = fdot2(w##f.w, hv.w, Z); }
#define ML(i, Z) { const uint4 wv = wl[t * NL + (i)]; \
    Z = fdot2(wv.x, hv.x, Z); Z = fdot2(wv.y, hv.y, Z); \
    Z = fdot2(wv.z, hv.z, Z); Z = fdot2(wv.w, hv.w, Z); }

__global__ __launch_bounds__(T, 2)
__attribute__((amdgpu_waves_per_eu(2, 2)))
void rnn_main(const float* __restrict__ x,  const float* __restrict__ bx,
              const float* __restrict__ bh, const float* __restrict__ Wy,
              const float* __restrict__ by, const uint4* __restrict__ Wpk,
              float* __restrict__ y) {
    __shared__ uint4 wl[T * NL];                     // 152 KB, transposed
    __shared__ __align__(16) __half hb2[2][DTOT];    // double-buffered h~

    const int b = blockIdx.x, t = threadIdx.x;
    const int s = t & 7;

    // ---- AGPR unlock: opaque touch of a127 so the attributor keeps the
    // AGPR class live -> allocator spills weight overflow to AGPRs, not
    // scratch. Never-true opaque guard keeps it un-DCE-able. ----
    {
        uint32_t agk;
        asm volatile("v_accvgpr_write_b32 a127, 0\n\t"
                     "s_nop 1\n\t"
                     "v_accvgpr_read_b32 %0, a127" : "=v"(agk));
        if (agk == 0xDEADBEEFu) hb2[0][0] = __float2half(0.0f);  // never
    }

    // ---- one-time: LDS weights (per-thread contiguous, stride 304 B) ----
    #pragma unroll
    for (int i = 0; i < NL; ++i)
        wl[t * NL + i] = Wpk[(size_t)(KL0 + i) * T + t];

    // ---- one-time: 53 weight frags as plain named SSA (w0..w52).
    // Allocator keeps ~24 in arch VGPRs, spills the rest to AGPRs. ----
#define DECL_WV(f) const uint4 w##f = Wpk[(size_t)(f) * T + t];
    DECL_WV(0)  DECL_WV(1)  DECL_WV(2)  DECL_WV(3)  DECL_WV(4)  DECL_WV(5)
    DECL_WV(6)  DECL_WV(7)  DECL_WV(8)  DECL_WV(9)  DECL_WV(10) DECL_WV(11)
    DECL_WV(12) DECL_WV(13) DECL_WV(14) DECL_WV(15) DECL_WV(16) DECL_WV(17)
    DECL_WV(18) DECL_WV(19) DECL_WV(20) DECL_WV(21) DECL_WV(22) DECL_WV(23)
    DECL_WV(24) DECL_WV(25) DECL_WV(26) DECL_WV(27) DECL_WV(28) DECL_WV(29)
    DECL_WV(30) DECL_WV(31) DECL_WV(32) DECL_WV(33) DECL_WV(34) DECL_WV(35)
    DECL_WV(36) DECL_WV(37) DECL_WV(38) DECL_WV(39) DECL_WV(40) DECL_WV(41)
    DECL_WV(42) DECL_WV(43) DECL_WV(44) DECL_WV(45) DECL_WV(46) DECL_WV(47)
    DECL_WV(48) DECL_WV(49) DECL_WV(50) DECL_WV(51) DECL_WV(52)
#undef DECL_WV

    const float bs = bx[t] + bh[t];        // bias of row t (= 8g+s)
    const float* xb = x + (size_t)b * SEQ * IN;

    hb2[0][t] = __float2half(0.0f);                     // h0 = 0
    if (t < IN) hb2[0][HID + t] = __float2half(xb[t]);  // x_0
    float xv = (t < IN) ? xb[IN + t] : 0.0f;            // x_1 prefetched
    __syncthreads();

    #pragma unroll 1
    for (int tt = 0; tt < SEQ; ++tt) {
        const int c = tt & 1;
        const uint4* hb = (const uint4*)(&hb2[c][0] + DSL * s);
        float z0 = 0.f, z1 = 0.f, z2 = 0.f, z3 = 0.f;
        float z4 = 0.f, z5 = 0.f, z6 = 0.f, z7 = 0.f;

        { const uint4 hv = hb[0];                      // k 0..7
          MV(0,z0) MV(1,z1) MV(2,z2) MV(3,z3) MV(4,z4) MV(5,z5) MV(6,z6) MV(7,z7) }
        { const uint4 hv = hb[1];                      // k 8..15
          MV(8,z0) MV(9,z1) MV(10,z2) MV(11,z3) MV(12,z4) MV(13,z5) MV(14,z6) MV(15,z7) }
        { const uint4 hv = hb[2];                      // k 16..23
          MV(16,z0) MV(17,z1) MV(18,z2) MV(19,z3) MV(20,z4) MV(21,z5) MV(22,z6) MV(23,z7) }
        { const uint4 hv = hb[3];                      // k 24..31
          MV(24,z0) MV(25,z1) MV(26,z2) MV(27,z3) MV(28,z4) MV(29,z5) MV(30,z6) MV(31,z7) }
        { const uint4 hv = hb[4];                      // k 32..39
          MV(32,z0) MV(33,z1) MV(34,z2) MV(35,z3) MV(36,z4) MV(37,z5) MV(38,z6) MV(39,z7) }
        { const uint4 hv = hb[5];                      // k 40..47
          MV(40,z0) MV(41,z1) MV(42,z2) MV(43,z3) MV(44,z4) MV(45,z5) MV(46,z6) MV(47,z7) }
        { const uint4 hv = hb[6];                      // k 48..55
          MV(48,z0) MV(49,z1) MV(50,z2) MV(51,z3) MV(52,z4) ML(0,z5) ML(1,z6) ML(2,z7) }
        { const uint4 hv = hb[7];                      // k 56..63
          ML(3,z0) ML(4,z1) ML(5,z2) ML(6,z3) ML(7,z4) ML(8,z5) ML(9,z6) ML(10,z7) }
        { const uint4 hv = hb[8];                      // k 64..71
          ML(11,z0) ML(12,z1) ML(13,z2) ML(14,z3) ML(15,z4) ML(16,z5) ML(17,z6) ML(18,z7) }

        // 8-way K-reduce (R11-verified): after the 3 symmetric stages every
        // lane of the 8-lane group holds the full sums z0..z7.
        z0 = dpp_add<0xB1>(z0); z0 = dpp_add<0x4E>(z0); z0 = dpp_add<0x141>(z0);
        z1 = dpp_add<0xB1>(z1); z1 = dpp_add<0x4E>(z1); z1 = dpp_add<0x141>(z1);
        z2 = dpp_add<0xB1>(z2); z2 = dpp_add<0x4E>(z2); z2 = dpp_add<0x141>(z2);
        z3 = dpp_add<0xB1>(z3); z3 = dpp_add<0x4E>(z3); z3 = dpp_add<0x141>(z3);
        z4 = dpp_add<0xB1>(z4); z4 = dpp_add<0x4E>(z4); z4 = dpp_add<0x141>(z4);
        z5 = dpp_add<0xB1>(z5); z5 = dpp_add<0x4E>(z5); z5 = dpp_add<0x141>(z5);
        z6 = dpp_add<0xB1>(z6); z6 = dpp_add<0x4E>(z6); z6 = dpp_add<0x141>(z6);
        z7 = dpp_add<0xB1>(z7); z7 = dpp_add<0x4E>(z7); z7 = dpp_add<0x141>(z7);

        // All-lane epilogue: lane s selects z_s (7 cndmask), one tanh,
        // contiguous ds_write_b16 (row written = 8g+s = t).
        const float za = (s & 1) ? z1 : z0;
        const float zb = (s & 1) ? z3 : z2;
        const float zc = (s & 1) ? z5 : z4;
        const float zd = (s & 1) ? z7 : z6;
        const float ze = (s & 2) ? zb : za;
        const float zf = (s & 2) ? zd : zc;
        const float zz = (s & 4) ? zf : ze;
        const float hh = 1.f - 2.f * __builtin_amdgcn_rcpf(__expf(2.f * (zz + bs)) + 1.f);
        hb2[c ^ 1][t] = __float2half(hh);

        if (t < IN) {
            hb2[c ^ 1][HID + t] = __float2half(xv);    // x_{tt+1}
            if (tt + 2 < SEQ) xv = xb[(size_t)(tt + 2) * IN + t];
        }
        __syncthreads();
    }

    // ---- epilogue: y = h_T @ Wy^T + by (final h in buffer 0) ----
    if (t < OUT) {
        float acc = by[t];
        const float* wy = Wy + (size_t)t * HID;
        #pragma unroll 8
        for (int j = 0; j < HID; ++j)
            acc = fmaf(wy[j], __half2float(hb2[0][j]), acc);
        y[(size_t)b * OUT + t] = acc;
    }
}

extern "C" void kernel_launch(void* const* d_in, const int* in_sizes, int n_in,
                              void* d_out, int out_size, void* d_ws, size_t ws_size,
                              hipStream_t stream) {
    const float* x  = (const float*)d_in[0];
    const float* Wx = (const float*)d_in[1];
    const float* bx = (const float*)d_in[2];
    const float* Wh = (const float*)d_in[3];
    const float* bh = (const float*)d_in[4];
    const float* Wy = (const float*)d_in[5];
    const float* by = (const float*)d_in[6];
    float* y = (float*)d_out;

    uint4* Wpk = (uint4*)d_ws;  // 72*512*16 B = 576 KB packed f16 fragments

    hipLaunchKernelGGL(prep_w, dim3(72 * T / 256), dim3(256), 0, stream,
                       Wh, Wx, Wpk);
    hipLaunchKernelGGL(rnn_main, dim3(BATCH), dim3(T), 0, stream,
                       x, bx, bh, Wy, by, Wpk, y);
}